// Round 17
// baseline (80.009 us; speedup 1.0000x reference)
//
#include <hip/hip_runtime.h>
#include <hip/hip_bf16.h>
#include <math.h>

#define BB 2
#define CC 32
#define C8 4
#define NN 4096
#define VST 72        // LDS V tile row stride in shorts
#define LOG2E 1.4426950408889634f

typedef __attribute__((ext_vector_type(8))) short short8;
typedef __attribute__((ext_vector_type(16))) float f32x16;

static __device__ __forceinline__ short f2bf(float x) {
    return __builtin_bit_cast(short, __float2bfloat16(x));
}
static __device__ __forceinline__ unsigned int pkbf(float a, float b) {
    unsigned int ua = __builtin_bit_cast(unsigned int, a) + 0x8000u;
    unsigned int ub = __builtin_bit_cast(unsigned int, b) + 0x8000u;
    return (ua >> 16) | (ub & 0xffff0000u);
}

// ---------------- K1: QKV projection + CAM gram (R12 body; grid x16 via bx=%328) ----
__global__ __launch_bounds__(256) void k1(const float* __restrict__ x,
    const float* __restrict__ wq, const float* __restrict__ bq,
    const float* __restrict__ wk, const float* __restrict__ bk,
    const float* __restrict__ wv, const float* __restrict__ bv,
    short* __restrict__ qpk, short* __restrict__ kpk, short* __restrict__ vbf,
    float* __restrict__ eng)
{
    int bx = blockIdx.x % 328;            // DIAG: x16 duplicate grids, same writes
    if (bx >= 64) {
        int w = threadIdx.x >> 6, lane = threadIdx.x & 63;
        int pp = (bx - 64)*4 + w;     // 0..1055
        int b = pp >= 528 ? 1 : 0;
        int t = pp - b*528;
        int c = 0, rem = t;
        while (rem >= CC - c) { rem -= CC - c; ++c; }
        int d = c + rem;
        const float4* xc = (const float4*)(x + ((size_t)b*CC + c)*NN);
        const float4* xd = (const float4*)(x + ((size_t)b*CC + d)*NN);
        float s = 0.f;
        for (int tt = lane; tt < NN/4; tt += 64) {
            float4 a = xc[tt], bb = xd[tt];
            s += a.x*bb.x + a.y*bb.y + a.z*bb.z + a.w*bb.w;
        }
        #pragma unroll
        for (int off = 32; off; off >>= 1) s += __shfl_down(s, off, 64);
        if (lane == 0) {
            eng[(b*CC + c)*CC + d] = s;
            eng[(b*CC + d)*CC + c] = s;
        }
        return;
    }
    __shared__ float swq[C8*CC], swk[C8*CC], swv[CC*CC], sbq[C8], sbk[C8], sbv[CC];
    int tid = threadIdx.x;
    for (int i = tid; i < C8*CC; i += 256) { swq[i] = wq[i]; swk[i] = wk[i]; }
    for (int i = tid; i < CC*CC; i += 256) swv[i] = wv[i];
    if (tid < C8) { sbq[tid] = bq[tid]; sbk[tid] = bk[tid]; }
    if (tid < CC) sbv[tid] = bv[tid];
    __syncthreads();
    int tl = tid & 127, oh = tid >> 7;
    int g = bx*128 + tl;                  // 0..8191
    int b = g >> 12; int n = g & (NN-1);
    const float* xb = x + (size_t)b*CC*NN + n;
    float xr[CC];
    #pragma unroll
    for (int c = 0; c < CC; ++c) xr[c] = xb[(size_t)c*NN];
    if (oh == 0) {
        float qv[C8], kv[C8];
        #pragma unroll
        for (int o = 0; o < C8; ++o) { qv[o] = sbq[o]; kv[o] = sbk[o]; }
        #pragma unroll
        for (int c = 0; c < CC; ++c) {
            float xc = xr[c];
            #pragma unroll
            for (int o = 0; o < C8; ++o) { qv[o] += swq[o*CC+c]*xc; kv[o] += swk[o*CC+c]*xc; }
        }
        short4 qs = make_short4(f2bf(qv[0]*LOG2E), f2bf(qv[1]*LOG2E),
                                f2bf(qv[2]*LOG2E), f2bf(qv[3]*LOG2E));
        short4 ks = make_short4(f2bf(kv[0]), f2bf(kv[1]), f2bf(kv[2]), f2bf(kv[3]));
        *(short4*)(qpk + ((size_t)b*NN + n)*4) = qs;
        *(short4*)(kpk + ((size_t)b*NN + n)*4) = ks;
    }
    int o0 = oh*16;
    #pragma unroll
    for (int o = 0; o < 16; ++o) {
        float av = sbv[o0+o];
        #pragma unroll
        for (int c = 0; c < CC; ++c) av += swv[(o0+o)*CC+c]*xr[c];
        vbf[((size_t)b*CC+o0+o)*NN + n] = f2bf(av);
    }
}

// ---------------- K2: R12 body exactly; grid x2 via blk = blockIdx.x & 255 ----
__global__ __launch_bounds__(1024, 4) void k2(const short* __restrict__ qpk,
    const short* __restrict__ kpk, const short* __restrict__ vbf,
    const float* __restrict__ eng, const float* __restrict__ wo,
    const float* __restrict__ bo, const float* __restrict__ gp,
    const float* __restrict__ gc, const float* __restrict__ x,
    float* __restrict__ out)
{
    __shared__ __align__(16) char smem[99328];

    int blk = blockIdx.x & 255;           // DIAG: x2 duplicate grid, same writes
    int b  = blk >> 7;
    int it = blk & 127;
    int i0 = it*32;
    int tid = threadIdx.x;
    int w = tid >> 6, lane = tid & 63;
    int qcol = lane & 31, h = lane >> 5;

    short* vbuf = (short*)smem + w*(32*VST);

    int rv = lane >> 1, ch = lane & 1;
    const short* vsrc = vbf + (size_t)b*CC*NN + (size_t)rv*NN + w*64 + ch*32;
    const short* ksrc = kpk + ((size_t)b*NN + w*64 + qcol)*4;

    short8 qf = {0,0,0,0,0,0,0,0};
    if (h == 0) {
        short4 qv = *(const short4*)(qpk + ((size_t)b*NN + i0 + qcol)*4);
        qf[0]=qv.x; qf[1]=qv.y; qf[2]=qv.z; qf[3]=qv.w;
    }

    f32x16 acc = {0,0,0,0,0,0,0,0,0,0,0,0,0,0,0,0};
    const f32x16 zz = {0,0,0,0,0,0,0,0,0,0,0,0,0,0,0,0};
    float se = 0.f;

    short8 cv0 = *(const short8*)(vsrc);
    short8 cv1 = *(const short8*)(vsrc + 8);
    short8 cv2 = *(const short8*)(vsrc + 16);
    short8 cv3 = *(const short8*)(vsrc + 24);
    short4 ck0 = *(const short4*)(ksrc);
    short4 ck1 = *(const short4*)(ksrc + 128);

    #pragma unroll
    for (int t = 0; t < 4; ++t) {
        int tn = t < 3 ? t + 1 : 3;
        short8 nv0 = *(const short8*)(vsrc + tn*1024);
        short8 nv1 = *(const short8*)(vsrc + tn*1024 + 8);
        short8 nv2 = *(const short8*)(vsrc + tn*1024 + 16);
        short8 nv3 = *(const short8*)(vsrc + tn*1024 + 24);
        short4 nk0 = *(const short4*)(ksrc + tn*4096);
        short4 nk1 = *(const short4*)(ksrc + tn*4096 + 128);

        short* wp = vbuf + rv*VST + ch*32;
        *(short8*)(wp)      = cv0;
        *(short8*)(wp + 8)  = cv1;
        *(short8*)(wp + 16) = cv2;
        *(short8*)(wp + 24) = cv3;

        const short* vrow = vbuf + qcol*VST;
        #pragma unroll
        for (int cI = 0; cI < 2; ++cI) {
            short8 kf = {0,0,0,0,0,0,0,0};
            if (h == 0) {
                short4 kk = cI ? ck1 : ck0;
                kf[0]=kk.x; kf[1]=kk.y; kf[2]=kk.z; kf[3]=kk.w;
            }
            f32x16 s = __builtin_amdgcn_mfma_f32_32x32x16_bf16(kf, qf, zz, 0, 0, 0);
            unsigned int u[8];
            #pragma unroll
            for (int g4 = 0; g4 < 4; ++g4) {
                float p0 = exp2f(s[4*g4]),   p1 = exp2f(s[4*g4+1]);
                float p2 = exp2f(s[4*g4+2]), p3 = exp2f(s[4*g4+3]);
                se += (p0+p1)+(p2+p3);
                u[2*g4]   = pkbf(p0,p1);
                u[2*g4+1] = pkbf(p2,p3);
            }
            int vo = cI*32 + 4*h;
            short4 a0 = *(const short4*)(vrow + vo);
            short4 a1 = *(const short4*)(vrow + vo + 8);
            short4 a2 = *(const short4*)(vrow + vo + 16);
            short4 a3 = *(const short4*)(vrow + vo + 24);
            short8 vf1 = {a0.x,a0.y,a0.z,a0.w, a1.x,a1.y,a1.z,a1.w};
            short8 pf1 = {(short)u[0],(short)(u[0]>>16),(short)u[1],(short)(u[1]>>16),
                          (short)u[2],(short)(u[2]>>16),(short)u[3],(short)(u[3]>>16)};
            acc = __builtin_amdgcn_mfma_f32_32x32x16_bf16(vf1, pf1, acc, 0, 0, 0);
            short8 vf2 = {a2.x,a2.y,a2.z,a2.w, a3.x,a3.y,a3.z,a3.w};
            short8 pf2 = {(short)u[4],(short)(u[4]>>16),(short)u[5],(short)(u[5]>>16),
                          (short)u[6],(short)(u[6]>>16),(short)u[7],(short)(u[7]>>16)};
            acc = __builtin_amdgcn_mfma_f32_32x32x16_bf16(vf2, pf2, acc, 0, 0, 0);
        }
        cv0 = nv0; cv1 = nv1; cv2 = nv2; cv3 = nv3;
        ck0 = nk0; ck1 = nk1;
    }

    se += __shfl_xor(se, 32, 64);

    // ================= in-block combine + CAM fold + projection =================
    __syncthreads();
    float* pamw = (float*)smem;      // [16][32*33]
    float* seL  = pamw + 16*1056;    // [16][32]
    float* sinv = seL  + 512;        // [32]
    float* pamn = sinv + 32;         // [32][33]
    float* xt   = pamn + 1056;       // [32][33]
    float* swo  = xt   + 1056;       // [32][33]
    float* swx  = swo  + 1056;       // [32][33]
    float* sc   = swx  + 1056;       // [32][33]
    float* seng = sc   + 1056;       // [1024]
    float* sbo  = seng + 1024;       // [32]
    float* swo2 = sbo  + 32;         // [32][33]

    #pragma unroll
    for (int r = 0; r < 16; ++r) {
        int c = (r&3) + 8*(r>>2) + 4*h;
        pamw[w*1056 + c*33 + qcol] = acc[r];
    }
    if (h == 0) seL[w*32 + qcol] = se;
    for (int i = tid; i < CC*CC; i += 1024) {
        int o = i >> 5, c2 = i & 31;
        seng[i] = eng[b*CC*CC + i];
        swo [o*33 + c2] = wo[o*64 + c2];
        swo2[o*33 + c2] = wo[o*64 + 32 + c2];
        xt  [o*33 + c2] = x[(size_t)b*CC*NN + (size_t)o*NN + i0 + c2];
    }
    if (tid < CC) sbo[tid] = bo[tid];
    __syncthreads();

    if (tid < CC) {
        float s = 0.f;
        #pragma unroll
        for (int w2 = 0; w2 < 16; ++w2) s += seL[w2*32 + tid];
        sinv[tid] = 1.f / s;
    } else if (tid >= 64 && tid < 64 + CC) {
        int r2 = tid - 64;
        float mn = seng[r2*32];
        #pragma unroll
        for (int d = 1; d < CC; ++d) mn = fminf(mn, seng[r2*32 + d]);
        float pv[CC]; float s = 0.f;
        #pragma unroll
        for (int d = 0; d < CC; ++d) { pv[d] = __expf(mn - seng[r2*32 + d]); s += pv[d]; }
        float inv = 1.f / s;
        #pragma unroll
        for (int d = 0; d < CC; ++d) sc[r2*33 + d] = pv[d]*inv;
    }
    __syncthreads();

    float gpv = gp[0], gcv = gc[0];
    for (int i = tid; i < CC*CC; i += 1024) {
        int c = i >> 5, q = i & 31;
        float s2 = 0.f;
        #pragma unroll
        for (int w2 = 0; w2 < 16; ++w2) s2 += pamw[w2*1056 + c*33 + q];
        pamn[c*33 + q] = gpv * s2 * sinv[q];
        float t2 = 0.f;
        #pragma unroll
        for (int c2 = 0; c2 < CC; ++c2) t2 += swo2[c*33 + c2] * sc[c2*33 + q];
        swx[c*33 + q] = swo[c*33 + q] + swo2[c*33 + q] + gcv * t2;
    }
    __syncthreads();

    int q = tid & 31, slot = (tid >> 5) & 31;
    float o0 = sbo[slot];
    #pragma unroll
    for (int c = 0; c < CC; ++c) {
        o0 += swo[slot*33 + c] * pamn[c*33 + q] + swx[slot*33 + c] * xt[c*33 + q];
    }
    out[(size_t)b*CC*NN + (size_t)slot*NN + i0 + q] = o0;
}

extern "C" void kernel_launch(void* const* d_in, const int* in_sizes, int n_in,
                              void* d_out, int out_size, void* d_ws, size_t ws_size,
                              hipStream_t stream)
{
    const float* x  = (const float*)d_in[0];
    const float* wq = (const float*)d_in[1];
    const float* bq = (const float*)d_in[2];
    const float* wk = (const float*)d_in[3];
    const float* bk = (const float*)d_in[4];
    const float* wv = (const float*)d_in[5];
    const float* bv = (const float*)d_in[6];
    const float* gp = (const float*)d_in[7];
    const float* gc = (const float*)d_in[8];
    const float* wo = (const float*)d_in[9];
    const float* bo = (const float*)d_in[10];

    char* wsb = (char*)d_ws;
    short* qpk = (short*)(wsb + 0);          // 65536 B
    short* kpk = (short*)(wsb + 65536);      // 65536 B
    short* vbf = (short*)(wsb + 131072);     // 524288 B
    float* eng = (float*)(wsb + 655360);     // 8192 B

    // DIAGNOSTIC: grid-multiplied duplicates (identical writes) lift k1/k2 above
    // the ~39us harness fills into rocprof's top-5 WITHOUT changing kernel codegen.
    k1<<<328*16, 256, 0, stream>>>(x, wq, bq, wk, bk, wv, bv, qpk, kpk, vbf, eng);
    k2<<<512, 1024, 0, stream>>>(qpk, kpk, vbf, eng, wo, bo, gp, gc, x, (float*)d_out);
}

// Round 18
// 29.914 us; speedup vs baseline: 2.6746x; 2.6746x over previous
//
#include <hip/hip_runtime.h>
#include <hip/hip_bf16.h>
#include <math.h>

#define BB 2
#define CC 32
#define C8 4
#define NN 4096
#define LOG2E 1.4426950408889634f

typedef __attribute__((ext_vector_type(8))) short short8;
typedef __attribute__((ext_vector_type(16))) float f32x16;

static __device__ __forceinline__ short f2bf(float x) {
    return __builtin_bit_cast(short, __float2bfloat16(x));
}
static __device__ __forceinline__ unsigned int pkbf(float a, float b) {
    unsigned int ua = __builtin_bit_cast(unsigned int, a) + 0x8000u;
    unsigned int ub = __builtin_bit_cast(unsigned int, b) + 0x8000u;
    return (ua >> 16) | (ub & 0xffff0000u);
}
// async global->LDS DMA, 16B per lane (dest = uniform base + lane*16)
static __device__ __forceinline__ void gld16(const void* g, void* l) {
    __builtin_amdgcn_global_load_lds(
        (const __attribute__((address_space(1))) unsigned int*)g,
        (__attribute__((address_space(3))) unsigned int*)l, 16, 0, 0);
}

// ---------------- K1: QKV projection (blocks 0..63) + CAM gram c<=d (blocks 64..327) ----
__global__ __launch_bounds__(256) void k1(const float* __restrict__ x,
    const float* __restrict__ wq, const float* __restrict__ bq,
    const float* __restrict__ wk, const float* __restrict__ bk,
    const float* __restrict__ wv, const float* __restrict__ bv,
    short* __restrict__ qpk, short* __restrict__ kpk, short* __restrict__ vbf,
    float* __restrict__ eng)
{
    if (blockIdx.x >= 64) {
        int w = threadIdx.x >> 6, lane = threadIdx.x & 63;
        int pp = (blockIdx.x - 64)*4 + w;     // 0..1055
        int b = pp >= 528 ? 1 : 0;
        int t = pp - b*528;
        int c = 0, rem = t;
        while (rem >= CC - c) { rem -= CC - c; ++c; }
        int d = c + rem;
        const float4* xc = (const float4*)(x + ((size_t)b*CC + c)*NN);
        const float4* xd = (const float4*)(x + ((size_t)b*CC + d)*NN);
        float s = 0.f;
        for (int tt = lane; tt < NN/4; tt += 64) {
            float4 a = xc[tt], bb = xd[tt];
            s += a.x*bb.x + a.y*bb.y + a.z*bb.z + a.w*bb.w;
        }
        #pragma unroll
        for (int off = 32; off; off >>= 1) s += __shfl_down(s, off, 64);
        if (lane == 0) {
            eng[(b*CC + c)*CC + d] = s;
            eng[(b*CC + d)*CC + c] = s;
        }
        return;
    }
    __shared__ float swq[C8*CC], swk[C8*CC], swv[CC*CC], sbq[C8], sbk[C8], sbv[CC];
    int tid = threadIdx.x;
    for (int i = tid; i < C8*CC; i += 256) { swq[i] = wq[i]; swk[i] = wk[i]; }
    for (int i = tid; i < CC*CC; i += 256) swv[i] = wv[i];
    if (tid < C8) { sbq[tid] = bq[tid]; sbk[tid] = bk[tid]; }
    if (tid < CC) sbv[tid] = bv[tid];
    __syncthreads();
    int tl = tid & 127, oh = tid >> 7;
    int g = blockIdx.x*128 + tl;          // 0..8191
    int b = g >> 12; int n = g & (NN-1);
    const float* xb = x + (size_t)b*CC*NN + n;
    float xr[CC];
    #pragma unroll
    for (int c = 0; c < CC; ++c) xr[c] = xb[(size_t)c*NN];
    if (oh == 0) {
        float qv[C8], kv[C8];
        #pragma unroll
        for (int o = 0; o < C8; ++o) { qv[o] = sbq[o]; kv[o] = sbk[o]; }
        #pragma unroll
        for (int c = 0; c < CC; ++c) {
            float xc = xr[c];
            #pragma unroll
            for (int o = 0; o < C8; ++o) { qv[o] += swq[o*CC+c]*xc; kv[o] += swk[o*CC+c]*xc; }
        }
        short4 qs = make_short4(f2bf(qv[0]*LOG2E), f2bf(qv[1]*LOG2E),
                                f2bf(qv[2]*LOG2E), f2bf(qv[3]*LOG2E));
        short4 ks = make_short4(f2bf(kv[0]), f2bf(kv[1]), f2bf(kv[2]), f2bf(kv[3]));
        *(short4*)(qpk + ((size_t)b*NN + n)*4) = qs;
        *(short4*)(kpk + ((size_t)b*NN + n)*4) = ks;
    }
    int o0 = oh*16;
    #pragma unroll
    for (int o = 0; o < 16; ++o) {
        float av = sbv[o0+o];
        #pragma unroll
        for (int c = 0; c < CC; ++c) av += swv[(o0+o)*CC+c]*xr[c];
        vbf[((size_t)b*CC+o0+o)*NN + n] = f2bf(av);
    }
}

// ---------------- K2: flash with DMA V-staging (despilled) + R12 tail ----------------
// 256 blocks = (b, 32-query tile), 1024 thr = 16 waves. Wave w covers keys
// {t*1024 + w*64}, t=0..3. V staged via global_load_lds (no VGPR ring, no ds_write),
// double-buffered 4KB tiles; reads use a 16B-granular XOR swizzle (row&7)<<4 that is
// pre-applied to the DMA's per-lane GLOBAL source address (LDS stays linear).
// K hoisted to 8xshort4 registers. Counted vmcnt(4) per tile; sched_barrier fences.
__global__ __launch_bounds__(1024, 4) void k2(const short* __restrict__ qpk,
    const short* __restrict__ kpk, const short* __restrict__ vbf,
    const float* __restrict__ eng, const float* __restrict__ wo,
    const float* __restrict__ bo, const float* __restrict__ gp,
    const float* __restrict__ gc, const float* __restrict__ x,
    float* __restrict__ out)
{
    __shared__ __align__(16) char smem[131072];   // 16 waves x 2 bufs x 4KB

    int blk = blockIdx.x;
    int b  = blk >> 7;
    int it = blk & 127;
    int i0 = it*32;
    int tid = threadIdx.x;
    int w = tid >> 6, lane = tid & 63;
    int qcol = lane & 31, h = lane >> 5;

    char* vb0 = smem + w*8192;            // buffers: vb0, vb0+4096

    // DMA source: lane covers 16B chunk; row = (lane>>3) + i*8, swizzled col byte
    int lrow = lane >> 3;                              // 0..7
    int cbl  = ((lane & 7) ^ (lrow & 7)) << 4;         // pre-swizzled source byte
    const char* vsb = (const char*)vbf;
    size_t srow = ((size_t)(b*CC + lrow))*NN + w*64;   // elements

    short8 qf = {0,0,0,0,0,0,0,0};
    if (h == 0) {
        short4 qv = *(const short4*)(qpk + ((size_t)b*NN + i0 + qcol)*4);
        qf[0]=qv.x; qf[1]=qv.y; qf[2]=qv.z; qf[3]=qv.w;
    }
    // K hoisted: kreg[2T]=tile T half 0, kreg[2T+1]=half 1
    const short* ksrc = kpk + ((size_t)b*NN + w*64 + qcol)*4;
    short4 kreg[8];
    #pragma unroll
    for (int t = 0; t < 8; ++t) kreg[t] = make_short4(0,0,0,0);
    if (h == 0) {
        #pragma unroll
        for (int t = 0; t < 8; ++t)
            kreg[t] = *(const short4*)(ksrc + (t>>1)*4096 + (t&1)*128);
    }

    f32x16 acc = {0,0,0,0,0,0,0,0,0,0,0,0,0,0,0,0};
    const f32x16 zz = {0,0,0,0,0,0,0,0,0,0,0,0,0,0,0,0};
    float se = 0.f;

    // prologue: DMA tile 0 -> buf0
    #pragma unroll
    for (int i = 0; i < 4; ++i)
        gld16(vsb + 2*(srow + (size_t)i*8*NN) + cbl, vb0 + i*1024);

    int rb = qcol << 7;                   // row*128 within tile
    int sw = (qcol & 7) << 4;             // read-side swizzle

    #pragma unroll
    for (int t = 0; t < 4; ++t) {
        char* cur = vb0 + (t & 1)*4096;
        if (t < 3) {
            char* nxt = vb0 + ((t + 1) & 1)*4096;
            #pragma unroll
            for (int i = 0; i < 4; ++i)
                gld16(vsb + 2*(srow + (size_t)i*8*NN + (t+1)*1024) + cbl, nxt + i*1024);
            asm volatile("s_waitcnt vmcnt(4)" ::: "memory");   // tile t landed
        } else {
            asm volatile("s_waitcnt vmcnt(0)" ::: "memory");
        }
        __builtin_amdgcn_sched_barrier(0);

        #pragma unroll
        for (int cI = 0; cI < 2; ++cI) {
            short4 kk = kreg[2*t + cI];
            short8 kf = {kk.x, kk.y, kk.z, kk.w, 0,0,0,0};
            f32x16 s = __builtin_amdgcn_mfma_f32_32x32x16_bf16(kf, qf, zz, 0, 0, 0);
            unsigned int u[8];
            #pragma unroll
            for (int g4 = 0; g4 < 4; ++g4) {
                float p0 = exp2f(s[4*g4]),   p1 = exp2f(s[4*g4+1]);
                float p2 = exp2f(s[4*g4+2]), p3 = exp2f(s[4*g4+3]);
                se += (p0+p1)+(p2+p3);
                u[2*g4]   = pkbf(p0,p1);
                u[2*g4+1] = pkbf(p2,p3);
            }
            int bo = 64*cI + 8*h;
            short4 a0 = *(const short4*)(cur + rb + ((bo +  0) ^ sw));
            short4 a1 = *(const short4*)(cur + rb + ((bo + 16) ^ sw));
            short4 a2 = *(const short4*)(cur + rb + ((bo + 32) ^ sw));
            short4 a3 = *(const short4*)(cur + rb + ((bo + 48) ^ sw));
            short8 vf1 = {a0.x,a0.y,a0.z,a0.w, a1.x,a1.y,a1.z,a1.w};
            short8 pf1 = {(short)u[0],(short)(u[0]>>16),(short)u[1],(short)(u[1]>>16),
                          (short)u[2],(short)(u[2]>>16),(short)u[3],(short)(u[3]>>16)};
            acc = __builtin_amdgcn_mfma_f32_32x32x16_bf16(vf1, pf1, acc, 0, 0, 0);
            short8 vf2 = {a2.x,a2.y,a2.z,a2.w, a3.x,a3.y,a3.z,a3.w};
            short8 pf2 = {(short)u[4],(short)(u[4]>>16),(short)u[5],(short)(u[5]>>16),
                          (short)u[6],(short)(u[6]>>16),(short)u[7],(short)(u[7]>>16)};
            acc = __builtin_amdgcn_mfma_f32_32x32x16_bf16(vf2, pf2, acc, 0, 0, 0);
        }
    }

    se += __shfl_xor(se, 32, 64);   // combine the two key-halves per q

    // ================= in-block combine + CAM fold + projection (R12 tail) =========
    __syncthreads();
    float* pamw = (float*)smem;      // [16][32*33]
    float* seL  = pamw + 16*1056;    // [16][32]
    float* sinv = seL  + 512;        // [32]
    float* pamn = sinv + 32;         // [32][33]
    float* xt   = pamn + 1056;       // [32][33]
    float* swo  = xt   + 1056;       // [32][33]
    float* swx  = swo  + 1056;       // [32][33]
    float* sc   = swx  + 1056;       // [32][33]
    float* seng = sc   + 1056;       // [1024]
    float* sbo  = seng + 1024;       // [32]
    float* swo2 = sbo  + 32;         // [32][33]

    #pragma unroll
    for (int r = 0; r < 16; ++r) {
        int c = (r&3) + 8*(r>>2) + 4*h;
        pamw[w*1056 + c*33 + qcol] = acc[r];
    }
    if (h == 0) seL[w*32 + qcol] = se;
    for (int i = tid; i < CC*CC; i += 1024) {
        int o = i >> 5, c2 = i & 31;
        seng[i] = eng[b*CC*CC + i];
        swo [o*33 + c2] = wo[o*64 + c2];
        swo2[o*33 + c2] = wo[o*64 + 32 + c2];
        xt  [o*33 + c2] = x[(size_t)b*CC*NN + (size_t)o*NN + i0 + c2];
    }
    if (tid < CC) sbo[tid] = bo[tid];
    __syncthreads();

    if (tid < CC) {
        float s = 0.f;
        #pragma unroll
        for (int w2 = 0; w2 < 16; ++w2) s += seL[w2*32 + tid];
        sinv[tid] = 1.f / s;
    } else if (tid >= 64 && tid < 64 + CC) {
        int r2 = tid - 64;
        float mn = seng[r2*32];
        #pragma unroll
        for (int d = 1; d < CC; ++d) mn = fminf(mn, seng[r2*32 + d]);
        float pv[CC]; float s = 0.f;
        #pragma unroll
        for (int d = 0; d < CC; ++d) { pv[d] = __expf(mn - seng[r2*32 + d]); s += pv[d]; }
        float inv = 1.f / s;
        #pragma unroll
        for (int d = 0; d < CC; ++d) sc[r2*33 + d] = pv[d]*inv;
    }
    __syncthreads();

    float gpv = gp[0], gcv = gc[0];
    for (int i = tid; i < CC*CC; i += 1024) {
        int c = i >> 5, q = i & 31;
        float s2 = 0.f;
        #pragma unroll
        for (int w2 = 0; w2 < 16; ++w2) s2 += pamw[w2*1056 + c*33 + q];
        pamn[c*33 + q] = gpv * s2 * sinv[q];
        float t2 = 0.f;
        #pragma unroll
        for (int c2 = 0; c2 < CC; ++c2) t2 += swo2[c*33 + c2] * sc[c2*33 + q];
        swx[c*33 + q] = swo[c*33 + q] + swo2[c*33 + q] + gcv * t2;
    }
    __syncthreads();

    int q = tid & 31, slot = (tid >> 5) & 31;
    float o0 = sbo[slot];
    #pragma unroll
    for (int c = 0; c < CC; ++c) {
        o0 += swo[slot*33 + c] * pamn[c*33 + q] + swx[slot*33 + c] * xt[c*33 + q];
    }
    out[(size_t)b*CC*NN + (size_t)slot*NN + i0 + q] = o0;
}

extern "C" void kernel_launch(void* const* d_in, const int* in_sizes, int n_in,
                              void* d_out, int out_size, void* d_ws, size_t ws_size,
                              hipStream_t stream)
{
    const float* x  = (const float*)d_in[0];
    const float* wq = (const float*)d_in[1];
    const float* bq = (const float*)d_in[2];
    const float* wk = (const float*)d_in[3];
    const float* bk = (const float*)d_in[4];
    const float* wv = (const float*)d_in[5];
    const float* bv = (const float*)d_in[6];
    const float* gp = (const float*)d_in[7];
    const float* gc = (const float*)d_in[8];
    const float* wo = (const float*)d_in[9];
    const float* bo = (const float*)d_in[10];

    char* wsb = (char*)d_ws;
    short* qpk = (short*)(wsb + 0);          // 65536 B
    short* kpk = (short*)(wsb + 65536);      // 65536 B
    short* vbf = (short*)(wsb + 131072);     // 524288 B
    float* eng = (float*)(wsb + 655360);     // 8192 B

    k1<<<328, 256, 0, stream>>>(x, wq, bq, wk, bk, wv, bv, qpk, kpk, vbf, eng);
    k2<<<BB*128, 1024, 0, stream>>>(qpk, kpk, vbf, eng, wo, bo, gp, gc, x, (float*)d_out);
}